// Round 1
// baseline (1100.202 us; speedup 1.0000x reference)
//
#include <hip/hip_runtime.h>
#include <math.h>

#define SCALE_F 0.17677669529663687f   // 32^-0.5

// ---------------------------------------------------------------------------
// GEMM: C[m][n] = sum_k A[m][k] * B[k][n] + bias[m]
// A: M x K row-major (weights, shared across batch)
// B: K x N (activations, per batch via strideB), C: M x N (per batch strideC)
// BM=BN=128, BK=16, 256 threads, 8x8 micro-tile per thread.
// ---------------------------------------------------------------------------
__global__ __launch_bounds__(256)
void gemm_bias_kernel(const float* __restrict__ A, const float* __restrict__ Bmat,
                      const float* __restrict__ bias, float* __restrict__ C,
                      int M, int N, int K, long strideB, long strideC)
{
    const int bm = blockIdx.x, bn = blockIdx.y, bz = blockIdx.z;
    const float* Bp = Bmat + (long)bz * strideB;
    float* Cp = C + (long)bz * strideC;
    __shared__ float As[16][128];   // A staged transposed: As[k][m]
    __shared__ float Bs[16][128];
    const int tid = threadIdx.x;
    const int tx = tid & 15, ty = tid >> 4;
    const int m0 = bm * 128, n0 = bn * 128;
    float acc[8][8];
    #pragma unroll
    for (int i = 0; i < 8; ++i)
        #pragma unroll
        for (int j = 0; j < 8; ++j) acc[i][j] = 0.f;

    for (int k0 = 0; k0 < K; k0 += 16) {
        #pragma unroll
        for (int it = 0; it < 2; ++it) {
            int slot = tid + it * 256;        // 0..511
            int r = slot >> 2;                // 0..127
            int cq = slot & 3;                // 0..3
            float4 av = *reinterpret_cast<const float4*>(&A[(long)(m0 + r) * K + k0 + cq * 4]);
            As[cq * 4 + 0][r] = av.x;
            As[cq * 4 + 1][r] = av.y;
            As[cq * 4 + 2][r] = av.z;
            As[cq * 4 + 3][r] = av.w;
        }
        #pragma unroll
        for (int it = 0; it < 2; ++it) {
            int slot = tid + it * 256;        // 0..511
            int r = slot >> 5;                // 0..15
            int cq = slot & 31;               // 0..31
            *reinterpret_cast<float4*>(&Bs[r][cq * 4]) =
                *reinterpret_cast<const float4*>(&Bp[(long)(k0 + r) * N + n0 + cq * 4]);
        }
        __syncthreads();
        #pragma unroll
        for (int kk = 0; kk < 16; ++kk) {
            float a[8], b[8];
            *reinterpret_cast<float4*>(&a[0]) = *reinterpret_cast<const float4*>(&As[kk][ty * 8]);
            *reinterpret_cast<float4*>(&a[4]) = *reinterpret_cast<const float4*>(&As[kk][ty * 8 + 4]);
            *reinterpret_cast<float4*>(&b[0]) = *reinterpret_cast<const float4*>(&Bs[kk][tx * 8]);
            *reinterpret_cast<float4*>(&b[4]) = *reinterpret_cast<const float4*>(&Bs[kk][tx * 8 + 4]);
            #pragma unroll
            for (int i = 0; i < 8; ++i)
                #pragma unroll
                for (int j = 0; j < 8; ++j)
                    acc[i][j] += a[i] * b[j];
        }
        __syncthreads();
    }

    #pragma unroll
    for (int i = 0; i < 8; ++i) {
        float bv = bias[m0 + ty * 8 + i];
        float4 v0 = make_float4(acc[i][0] + bv, acc[i][1] + bv, acc[i][2] + bv, acc[i][3] + bv);
        float4 v1 = make_float4(acc[i][4] + bv, acc[i][5] + bv, acc[i][6] + bv, acc[i][7] + bv);
        float* crow = &Cp[(long)(m0 + ty * 8 + i) * N + n0 + tx * 8];
        *reinterpret_cast<float4*>(crow) = v0;
        *reinterpret_cast<float4*>(crow + 4) = v1;
    }
}

// ---------------------------------------------------------------------------
// Depthwise 5x5 conv (pad 2) over v channels of qkv.  grid (384, 8)
// ---------------------------------------------------------------------------
__global__ __launch_bounds__(256)
void lepe_kernel(const float* __restrict__ qkv, const float* __restrict__ w5,
                 const float* __restrict__ wb, float* __restrict__ lepe)
{
    const int ch = blockIdx.x;    // 0..383
    const int b = blockIdx.y;     // 0..7
    const float* src = qkv + ((long)b * 1152 + 768 + ch) * 4096;
    float* dst = lepe + ((long)b * 384 + ch) * 4096;
    __shared__ float tile[68 * 68];
    const int tid = threadIdx.x;
    for (int i = tid; i < 68 * 68; i += 256) {
        int y = i / 68 - 2, x = i % 68 - 2;
        tile[i] = (y >= 0 && y < 64 && x >= 0 && x < 64) ? src[y * 64 + x] : 0.f;
    }
    float f[25];
    #pragma unroll
    for (int j = 0; j < 25; ++j) f[j] = w5[ch * 25 + j];
    float bv = wb[ch];
    __syncthreads();
    for (int p = tid; p < 4096; p += 256) {
        int y = p >> 6, x = p & 63;
        float acc = bv;
        #pragma unroll
        for (int dy = 0; dy < 5; ++dy)
            #pragma unroll
            for (int dx = 0; dx < 5; ++dx)
                acc += tile[(y + dy) * 68 + (x + dx)] * f[dy * 5 + dx];
        dst[p] = acc;
    }
}

// ---------------------------------------------------------------------------
// cos kernel: per (b,n) compute cls = normalized mean of k, then
// cos[l] = cls_hat . k_hat[l].  grid 96 blocks x 256 threads.
// fp64 reductions to keep ordering faithful to the fp32 reference.
// ---------------------------------------------------------------------------
__global__ __launch_bounds__(256)
void cos_kernel(const float* __restrict__ qkv, float* __restrict__ cosv)
{
    const int bn = blockIdx.x;    // 0..95
    const int b = bn / 12, n = bn % 12;
    const float* kb = qkv + ((long)b * 1152 + 384 + n * 32) * 4096;
    __shared__ float part[256][33];
    __shared__ float clsn[32];
    const int tid = threadIdx.x;
    float acc[32];
    #pragma unroll
    for (int d = 0; d < 32; ++d) acc[d] = 0.f;
    for (int i = 0; i < 16; ++i) {
        int tok = tid + i * 256;
        #pragma unroll
        for (int d = 0; d < 32; ++d) acc[d] += kb[(long)d * 4096 + tok];
    }
    #pragma unroll
    for (int d = 0; d < 32; ++d) part[tid][d] = acc[d];
    __syncthreads();
    if (tid < 32) {
        double s = 0.0;
        for (int t = 0; t < 256; ++t) s += (double)part[t][tid];
        part[0][tid] = (float)s;  // keep rounded; direction only, normalized below
        // store exact double halves? direction accuracy ~1e-8 suffices at float
    }
    __syncthreads();
    if (tid == 0) {
        double nn = 0.0;
        for (int d = 0; d < 32; ++d) { double v = (double)part[0][d]; nn += v * v; }
        double inv = 1.0 / sqrt(nn > 1e-300 ? nn : 1e-300);
        for (int d = 0; d < 32; ++d) clsn[d] = (float)((double)part[0][d] * inv);
    }
    __syncthreads();
    for (int i = 0; i < 16; ++i) {
        int tok = tid + i * 256;
        double dot = 0.0, nrm = 0.0;
        #pragma unroll
        for (int d = 0; d < 32; ++d) {
            float kv = kb[(long)d * 4096 + tok];
            dot += (double)clsn[d] * (double)kv;
            nrm += (double)kv * (double)kv;
        }
        double c = dot / sqrt(nrm > 1e-300 ? nrm : 1e-300);
        cosv[(long)bn * 4096 + tok] = (float)c;
    }
}

// ---------------------------------------------------------------------------
// Bitonic argsort ascending by (cos, idx) — matches stable jnp.argsort.
// grid 96 blocks x 512 threads, LDS 32KB.
// ---------------------------------------------------------------------------
__global__ __launch_bounds__(512)
void sort_kernel(const float* __restrict__ cosv, int* __restrict__ idxo)
{
    const int bn = blockIdx.x;
    __shared__ float sv[4096];
    __shared__ int si[4096];
    const int tid = threadIdx.x;
    for (int i = tid; i < 4096; i += 512) { sv[i] = cosv[(long)bn * 4096 + i]; si[i] = i; }
    __syncthreads();
    for (int size = 2; size <= 4096; size <<= 1) {
        for (int stride = size >> 1; stride >= 1; stride >>= 1) {
            for (int i = tid; i < 2048; i += 512) {
                int lo = (i << 1) - (i & (stride - 1));
                int hi = lo + stride;
                bool asc = ((lo & size) == 0);
                float av = sv[lo], bv = sv[hi];
                int ai = si[lo], bi = si[hi];
                bool agtb = (av > bv) || (av == bv && ai > bi);
                if (agtb == asc) {
                    sv[lo] = bv; sv[hi] = av;
                    si[lo] = bi; si[hi] = ai;
                }
            }
            __syncthreads();
        }
    }
    for (int i = tid; i < 4096; i += 512) idxo[(long)bn * 4096 + i] = si[i];
}

// ---------------------------------------------------------------------------
// Clustered attention. grid (16 clusters, 12 heads, 8 batch), 256 threads.
// k,v gathered to LDS (k pre-scaled); thread t = query row t; online softmax.
// Epilogue: res = o/den + lepe written at ORIGINAL token position (inverse
// gather), overwriting the dead q region of qkv.
// ---------------------------------------------------------------------------
__global__ __launch_bounds__(256)
void attn_kernel(const float* __restrict__ qkv, const int* __restrict__ idxbuf,
                 const float* __restrict__ lepe, float* __restrict__ resout)
{
    const int c = blockIdx.x, n = blockIdx.y, b = blockIdx.z;
    const float* qb = qkv + ((long)b * 1152 + n * 32) * 4096;
    const float* kb = qb + (long)384 * 4096;
    const float* vb = qb + (long)768 * 4096;
    const float* lp = lepe + ((long)b * 384 + n * 32) * 4096;
    float* ob = resout + ((long)b * 1152 + n * 32) * 4096;
    const int* ip = idxbuf + ((long)(b * 12 + n)) * 4096 + c * 256;

    __shared__ int tok[256];
    __shared__ float ks[256][32];
    __shared__ float vs[256][32];
    const int tid = threadIdx.x;
    tok[tid] = ip[tid];
    __syncthreads();
    {
        int t = tok[tid];
        #pragma unroll
        for (int dq = 0; dq < 8; ++dq) {
            float4 kv, vv;
            kv.x = kb[(long)(dq * 4 + 0) * 4096 + t] * SCALE_F;
            kv.y = kb[(long)(dq * 4 + 1) * 4096 + t] * SCALE_F;
            kv.z = kb[(long)(dq * 4 + 2) * 4096 + t] * SCALE_F;
            kv.w = kb[(long)(dq * 4 + 3) * 4096 + t] * SCALE_F;
            vv.x = vb[(long)(dq * 4 + 0) * 4096 + t];
            vv.y = vb[(long)(dq * 4 + 1) * 4096 + t];
            vv.z = vb[(long)(dq * 4 + 2) * 4096 + t];
            vv.w = vb[(long)(dq * 4 + 3) * 4096 + t];
            *reinterpret_cast<float4*>(&ks[tid][dq * 4]) = kv;
            *reinterpret_cast<float4*>(&vs[tid][dq * 4]) = vv;
        }
    }
    __syncthreads();

    const int tm = tok[tid];
    float q[32];
    #pragma unroll
    for (int d = 0; d < 32; ++d) q[d] = qb[(long)d * 4096 + tm];
    float o[32];
    #pragma unroll
    for (int d = 0; d < 32; ++d) o[d] = 0.f;
    float mx = -INFINITY, den = 0.f;

    for (int jt = 0; jt < 256; jt += 8) {
        float s[8];
        #pragma unroll
        for (int jj = 0; jj < 8; ++jj) {
            const float* kr = &ks[jt + jj][0];
            float a = 0.f;
            #pragma unroll
            for (int d = 0; d < 32; ++d) a += q[d] * kr[d];
            s[jj] = a;
        }
        float tmax = s[0];
        #pragma unroll
        for (int jj = 1; jj < 8; ++jj) tmax = fmaxf(tmax, s[jj]);
        if (tmax > mx) {
            float f = __expf(mx - tmax);
            den *= f;
            #pragma unroll
            for (int d = 0; d < 32; ++d) o[d] *= f;
            mx = tmax;
        }
        #pragma unroll
        for (int jj = 0; jj < 8; ++jj) {
            float p = __expf(s[jj] - mx);
            den += p;
            const float* vr = &vs[jt + jj][0];
            #pragma unroll
            for (int d = 0; d < 32; ++d) o[d] += p * vr[d];
        }
    }
    float inv = 1.f / den;
    #pragma unroll
    for (int d = 0; d < 32; ++d)
        ob[(long)d * 4096 + tm] = o[d] * inv + lp[(long)d * 4096 + tm];
}

// ---------------------------------------------------------------------------
extern "C" void kernel_launch(void* const* d_in, const int* in_sizes, int n_in,
                              void* d_out, int out_size, void* d_ws, size_t ws_size,
                              hipStream_t stream)
{
    const float* x      = (const float*)d_in[0];
    const float* qkv_w  = (const float*)d_in[1];
    const float* qkv_b  = (const float*)d_in[2];
    const float* lepe_w = (const float*)d_in[3];
    const float* lepe_b = (const float*)d_in[4];
    const float* out_w  = (const float*)d_in[5];
    const float* out_b  = (const float*)d_in[6];
    float* out = (float*)d_out;

    char* ws = (char*)d_ws;
    float* qkv  = (float*)ws;                                   // 8*1152*4096 f32 = 151 MB
    float* cosv = (float*)(ws + 150994944);                     // 96*4096 f32
    int*   idx  = (int*)  (ws + 150994944 + 1572864);           // 96*4096 i32
    float* lepe = out;                                          // borrow d_out (50MB), fully
                                                                // overwritten by final GEMM

    // 1) QKV projection
    dim3 g1(1152 / 128, 4096 / 128, 8);
    gemm_bias_kernel<<<g1, 256, 0, stream>>>(qkv_w, x, qkv_b, qkv,
                                             1152, 4096, 384,
                                             (long)384 * 4096, (long)1152 * 4096);
    // 2) LePE depthwise conv on V
    lepe_kernel<<<dim3(384, 8), 256, 0, stream>>>(qkv, lepe_w, lepe_b, lepe);
    // 3) cosine-to-class-mean per (b, head)
    cos_kernel<<<96, 256, 0, stream>>>(qkv, cosv);
    // 4) stable ascending argsort
    sort_kernel<<<96, 512, 0, stream>>>(cosv, idx);
    // 5) clustered attention + inverse scatter + lepe residual (writes q region)
    attn_kernel<<<dim3(16, 12, 8), 256, 0, stream>>>(qkv, idx, lepe, qkv);
    // 6) output projection
    dim3 g2(384 / 128, 4096 / 128, 8);
    gemm_bias_kernel<<<g2, 256, 0, stream>>>(out_w, qkv, out_b, out,
                                             384, 4096, 384,
                                             (long)1152 * 4096, (long)384 * 4096);
}

// Round 2
// 985.039 us; speedup vs baseline: 1.1169x; 1.1169x over previous
//
#include <hip/hip_runtime.h>
#include <math.h>

#define SCALE_F 0.17677669529663687f   // 32^-0.5

// ---------------------------------------------------------------------------
// GEMM1: C[m][n] = sum_k A[m][k]*B[k][n] + bias[m], stored TRANSPOSED:
// CT[n][m] (token-major).  A: MxK row-major. B: KxN per-batch. 128x128x16.
// ---------------------------------------------------------------------------
__global__ __launch_bounds__(256)
void gemm_storeT_kernel(const float* __restrict__ A, const float* __restrict__ Bmat,
                        const float* __restrict__ bias, float* __restrict__ CT,
                        int M, int N, int K, long strideB, long strideCT, int ldct)
{
    const int bm = blockIdx.x, bn = blockIdx.y, bz = blockIdx.z;
    const float* Bp = Bmat + (long)bz * strideB;
    float* Cp = CT + (long)bz * strideCT;
    __shared__ float As[16][132];   // As[k][m]
    __shared__ float Bs[16][132];   // Bs[k][n]
    const int tid = threadIdx.x;
    const int tx = tid & 15, ty = tid >> 4;
    const int m0 = bm * 128, n0 = bn * 128;
    float acc[8][8];
    #pragma unroll
    for (int i = 0; i < 8; ++i)
        #pragma unroll
        for (int j = 0; j < 8; ++j) acc[i][j] = 0.f;

    for (int k0 = 0; k0 < K; k0 += 16) {
        #pragma unroll
        for (int it = 0; it < 2; ++it) {
            int slot = tid + it * 256;
            int r = slot >> 2, cq = slot & 3;
            float4 av = *reinterpret_cast<const float4*>(&A[(long)(m0 + r) * K + k0 + cq * 4]);
            As[cq * 4 + 0][r] = av.x; As[cq * 4 + 1][r] = av.y;
            As[cq * 4 + 2][r] = av.z; As[cq * 4 + 3][r] = av.w;
        }
        #pragma unroll
        for (int it = 0; it < 2; ++it) {
            int slot = tid + it * 256;
            int r = slot >> 5, cq = slot & 31;
            *reinterpret_cast<float4*>(&Bs[r][cq * 4]) =
                *reinterpret_cast<const float4*>(&Bp[(long)(k0 + r) * N + n0 + cq * 4]);
        }
        __syncthreads();
        #pragma unroll
        for (int kk = 0; kk < 16; ++kk) {
            float a[8], b[8];
            *reinterpret_cast<float4*>(&a[0]) = *reinterpret_cast<const float4*>(&As[kk][ty * 8]);
            *reinterpret_cast<float4*>(&a[4]) = *reinterpret_cast<const float4*>(&As[kk][ty * 8 + 4]);
            *reinterpret_cast<float4*>(&b[0]) = *reinterpret_cast<const float4*>(&Bs[kk][tx * 8]);
            *reinterpret_cast<float4*>(&b[4]) = *reinterpret_cast<const float4*>(&Bs[kk][tx * 8 + 4]);
            #pragma unroll
            for (int i = 0; i < 8; ++i)
                #pragma unroll
                for (int j = 0; j < 8; ++j)
                    acc[i][j] += a[i] * b[j];
        }
        __syncthreads();
    }

    float bv[8];
    #pragma unroll
    for (int i = 0; i < 8; ++i) bv[i] = bias[m0 + ty * 8 + i];
    #pragma unroll
    for (int j = 0; j < 8; ++j) {
        long tok = n0 + tx * 8 + j;
        float* p = Cp + tok * ldct + m0 + ty * 8;
        float4 lo = make_float4(acc[0][j] + bv[0], acc[1][j] + bv[1], acc[2][j] + bv[2], acc[3][j] + bv[3]);
        float4 hi = make_float4(acc[4][j] + bv[4], acc[5][j] + bv[5], acc[6][j] + bv[6], acc[7][j] + bv[7]);
        *reinterpret_cast<float4*>(p) = lo;
        *reinterpret_cast<float4*>(p + 4) = hi;
    }
}

// ---------------------------------------------------------------------------
// GEMM2: C[m][n] = sum_k A[m][k]*BT[n][k] + bias[m]  (B token-major, strided)
// ---------------------------------------------------------------------------
__global__ __launch_bounds__(256)
void gemm_bt_kernel(const float* __restrict__ A, const float* __restrict__ BT,
                    const float* __restrict__ bias, float* __restrict__ C,
                    int M, int N, int K, int ldbt, long strideBT, long strideC)
{
    const int bm = blockIdx.x, bn = blockIdx.y, bz = blockIdx.z;
    const float* Bp = BT + (long)bz * strideBT;
    float* Cp = C + (long)bz * strideC;
    __shared__ float As[16][132];
    __shared__ float Bs[16][132];
    const int tid = threadIdx.x;
    const int tx = tid & 15, ty = tid >> 4;
    const int m0 = bm * 128, n0 = bn * 128;
    float acc[8][8];
    #pragma unroll
    for (int i = 0; i < 8; ++i)
        #pragma unroll
        for (int j = 0; j < 8; ++j) acc[i][j] = 0.f;

    for (int k0 = 0; k0 < K; k0 += 16) {
        #pragma unroll
        for (int it = 0; it < 2; ++it) {
            int slot = tid + it * 256;
            int r = slot >> 2, cq = slot & 3;
            float4 av = *reinterpret_cast<const float4*>(&A[(long)(m0 + r) * K + k0 + cq * 4]);
            As[cq * 4 + 0][r] = av.x; As[cq * 4 + 1][r] = av.y;
            As[cq * 4 + 2][r] = av.z; As[cq * 4 + 3][r] = av.w;
        }
        #pragma unroll
        for (int it = 0; it < 2; ++it) {
            int slot = tid + it * 256;
            int n = slot >> 2, q = slot & 3;
            float4 bv4 = *reinterpret_cast<const float4*>(&Bp[(long)(n0 + n) * ldbt + k0 + q * 4]);
            Bs[q * 4 + 0][n] = bv4.x; Bs[q * 4 + 1][n] = bv4.y;
            Bs[q * 4 + 2][n] = bv4.z; Bs[q * 4 + 3][n] = bv4.w;
        }
        __syncthreads();
        #pragma unroll
        for (int kk = 0; kk < 16; ++kk) {
            float a[8], b[8];
            *reinterpret_cast<float4*>(&a[0]) = *reinterpret_cast<const float4*>(&As[kk][ty * 8]);
            *reinterpret_cast<float4*>(&a[4]) = *reinterpret_cast<const float4*>(&As[kk][ty * 8 + 4]);
            *reinterpret_cast<float4*>(&b[0]) = *reinterpret_cast<const float4*>(&Bs[kk][tx * 8]);
            *reinterpret_cast<float4*>(&b[4]) = *reinterpret_cast<const float4*>(&Bs[kk][tx * 8 + 4]);
            #pragma unroll
            for (int i = 0; i < 8; ++i)
                #pragma unroll
                for (int j = 0; j < 8; ++j)
                    acc[i][j] += a[i] * b[j];
        }
        __syncthreads();
    }

    #pragma unroll
    for (int i = 0; i < 8; ++i) {
        float bv = bias[m0 + ty * 8 + i];
        float4 v0 = make_float4(acc[i][0] + bv, acc[i][1] + bv, acc[i][2] + bv, acc[i][3] + bv);
        float4 v1 = make_float4(acc[i][4] + bv, acc[i][5] + bv, acc[i][6] + bv, acc[i][7] + bv);
        float* crow = &Cp[(long)(m0 + ty * 8 + i) * N + n0 + tx * 8];
        *reinterpret_cast<float4*>(crow) = v0;
        *reinterpret_cast<float4*>(crow + 4) = v1;
    }
}

// ---------------------------------------------------------------------------
// Depthwise 5x5 conv (pad 2), token-major in (v region of qkvT) and out lepeT.
// grid (chtile=24, ytile=8, b=8), 256 thr. LDS tile [12][68][16] f32 = 52KB.
// thread: c = tid&15 (channel), xo = tid>>4.
// ---------------------------------------------------------------------------
__global__ __launch_bounds__(256)
void lepe_kernel(const float* __restrict__ qkvT, const float* __restrict__ w5,
                 const float* __restrict__ wb, float* __restrict__ lepeT)
{
    const int ch0 = blockIdx.x * 16;
    const int y0 = blockIdx.y * 8;
    const int b = blockIdx.z;
    const float* vb = qkvT + (long)b * 4096 * 1152 + 768 + ch0;
    float* dst = lepeT + (long)b * 4096 * 384 + ch0;
    __shared__ float tile[12 * 68 * 16];
    const int tid = threadIdx.x;

    for (int i = tid; i < 12 * 68 * 16; i += 256) {
        int pix = i >> 4, c = i & 15;
        int yy = pix / 68, xx = pix % 68;
        int gy = y0 + yy - 2, gx = xx - 2;
        float v = 0.f;
        if (gy >= 0 && gy < 64 && gx >= 0 && gx < 64)
            v = vb[(long)(gy * 64 + gx) * 1152 + c];
        tile[i] = v;
    }
    const int c = tid & 15, xo = tid >> 4;
    float f[25];
    #pragma unroll
    for (int j = 0; j < 25; ++j) f[j] = w5[(ch0 + c) * 25 + j];
    const float bv = wb[ch0 + c];
    __syncthreads();

    #pragma unroll
    for (int yy = 0; yy < 8; ++yy) {
        #pragma unroll
        for (int xq = 0; xq < 4; ++xq) {
            int x = xq * 16 + xo;
            float acc = bv;
            #pragma unroll
            for (int dy = 0; dy < 5; ++dy)
                #pragma unroll
                for (int dx = 0; dx < 5; ++dx)
                    acc += tile[((yy + dy) * 68 + (x + dx)) * 16 + c] * f[dy * 5 + dx];
            dst[(long)((y0 + yy) * 64 + x) * 384 + c] = acc;
        }
    }
}

// ---------------------------------------------------------------------------
// cos kernel (token-major reads). grid 96 x 256.
// ---------------------------------------------------------------------------
__global__ __launch_bounds__(256)
void cos_kernel(const float* __restrict__ qkvT, float* __restrict__ cosv)
{
    const int bn = blockIdx.x;
    const int b = bn / 12, n = bn % 12;
    const float* kb = qkvT + (long)b * 4096 * 1152 + 384 + n * 32;
    __shared__ float part[256][33];
    __shared__ float clsn[32];
    const int tid = threadIdx.x;
    float acc[32];
    #pragma unroll
    for (int d = 0; d < 32; ++d) acc[d] = 0.f;
    for (int i = 0; i < 16; ++i) {
        long tok = tid + i * 256;
        const float* kr = kb + tok * 1152;
        #pragma unroll
        for (int d = 0; d < 32; ++d) acc[d] += kr[d];
    }
    #pragma unroll
    for (int d = 0; d < 32; ++d) part[tid][d] = acc[d];
    __syncthreads();
    if (tid < 32) {
        double s = 0.0;
        for (int t = 0; t < 256; ++t) s += (double)part[t][tid];
        part[0][tid] = (float)s;
    }
    __syncthreads();
    if (tid == 0) {
        double nn = 0.0;
        for (int d = 0; d < 32; ++d) { double v = (double)part[0][d]; nn += v * v; }
        double inv = 1.0 / sqrt(nn > 1e-300 ? nn : 1e-300);
        for (int d = 0; d < 32; ++d) clsn[d] = (float)((double)part[0][d] * inv);
    }
    __syncthreads();
    for (int i = 0; i < 16; ++i) {
        long tok = tid + i * 256;
        const float* kr = kb + tok * 1152;
        double dot = 0.0, nrm = 0.0;
        #pragma unroll
        for (int d = 0; d < 32; ++d) {
            float kv = kr[d];
            dot += (double)clsn[d] * (double)kv;
            nrm += (double)kv * (double)kv;
        }
        double cv = dot / sqrt(nrm > 1e-300 ? nrm : 1e-300);
        cosv[(long)bn * 4096 + tok] = (float)cv;
    }
}

// ---------------------------------------------------------------------------
// Bitonic argsort ascending by (cos, idx) — matches stable jnp.argsort.
// ---------------------------------------------------------------------------
__global__ __launch_bounds__(512)
void sort_kernel(const float* __restrict__ cosv, int* __restrict__ idxo)
{
    const int bn = blockIdx.x;
    __shared__ float sv[4096];
    __shared__ int si[4096];
    const int tid = threadIdx.x;
    for (int i = tid; i < 4096; i += 512) { sv[i] = cosv[(long)bn * 4096 + i]; si[i] = i; }
    __syncthreads();
    for (int size = 2; size <= 4096; size <<= 1) {
        for (int stride = size >> 1; stride >= 1; stride >>= 1) {
            for (int i = tid; i < 2048; i += 512) {
                int lo = (i << 1) - (i & (stride - 1));
                int hi = lo + stride;
                bool asc = ((lo & size) == 0);
                float av = sv[lo], bvv = sv[hi];
                int ai = si[lo], bi = si[hi];
                bool agtb = (av > bvv) || (av == bvv && ai > bi);
                if (agtb == asc) {
                    sv[lo] = bvv; sv[hi] = av;
                    si[lo] = bi; si[hi] = ai;
                }
            }
            __syncthreads();
        }
    }
    for (int i = tid; i < 4096; i += 512) idxo[(long)bn * 4096 + i] = si[i];
}

// ---------------------------------------------------------------------------
// Clustered attention, token-major. grid (16,12,8), 256 thr.
// LDS rows padded to 33 (bank-conflict-free staging). res = o/den + lepe
// written into the (dead) q columns of qkvT at the original token position.
// ---------------------------------------------------------------------------
__global__ __launch_bounds__(256)
void attn_kernel(float* __restrict__ qkvT, const int* __restrict__ idxbuf,
                 const float* __restrict__ lepeT)
{
    const int cc = blockIdx.x, n = blockIdx.y, b = blockIdx.z;
    const int* ip = idxbuf + ((long)(b * 12 + n)) * 4096 + cc * 256;
    __shared__ float ks[256][33];
    __shared__ float vs[256][33];
    const int tid = threadIdx.x;

    const int t = ip[tid];
    float* base = qkvT + ((long)b * 4096 + t) * 1152 + n * 32;
    float q[32];
    #pragma unroll
    for (int dq = 0; dq < 8; ++dq) {
        float4 qv = *reinterpret_cast<const float4*>(base + dq * 4);
        float4 kv = *reinterpret_cast<const float4*>(base + 384 + dq * 4);
        float4 vv = *reinterpret_cast<const float4*>(base + 768 + dq * 4);
        q[dq * 4 + 0] = qv.x; q[dq * 4 + 1] = qv.y; q[dq * 4 + 2] = qv.z; q[dq * 4 + 3] = qv.w;
        kv.x *= SCALE_F; kv.y *= SCALE_F; kv.z *= SCALE_F; kv.w *= SCALE_F;
        *reinterpret_cast<float4*>(&ks[tid][dq * 4]) = kv;
        *reinterpret_cast<float4*>(&vs[tid][dq * 4]) = vv;
    }
    __syncthreads();

    float o[32];
    #pragma unroll
    for (int d = 0; d < 32; ++d) o[d] = 0.f;
    float mx = -INFINITY, den = 0.f;

    for (int jt = 0; jt < 256; jt += 8) {
        float s[8];
        #pragma unroll
        for (int jj = 0; jj < 8; ++jj) {
            const float* kr = &ks[jt + jj][0];
            float a = 0.f;
            #pragma unroll
            for (int d = 0; d < 32; ++d) a += q[d] * kr[d];
            s[jj] = a;
        }
        float tmax = s[0];
        #pragma unroll
        for (int jj = 1; jj < 8; ++jj) tmax = fmaxf(tmax, s[jj]);
        if (tmax > mx) {
            float f = __expf(mx - tmax);
            den *= f;
            #pragma unroll
            for (int d = 0; d < 32; ++d) o[d] *= f;
            mx = tmax;
        }
        #pragma unroll
        for (int jj = 0; jj < 8; ++jj) {
            float p = __expf(s[jj] - mx);
            den += p;
            const float* vr = &vs[jt + jj][0];
            #pragma unroll
            for (int d = 0; d < 32; ++d) o[d] += p * vr[d];
        }
    }
    const float inv = 1.f / den;
    const float* lp = lepeT + ((long)b * 4096 + t) * 384 + n * 32;
    #pragma unroll
    for (int dq = 0; dq < 8; ++dq) {
        float4 lv = *reinterpret_cast<const float4*>(lp + dq * 4);
        float4 ov;
        ov.x = o[dq * 4 + 0] * inv + lv.x;
        ov.y = o[dq * 4 + 1] * inv + lv.y;
        ov.z = o[dq * 4 + 2] * inv + lv.z;
        ov.w = o[dq * 4 + 3] * inv + lv.w;
        *reinterpret_cast<float4*>(base + dq * 4) = ov;
    }
}

// ---------------------------------------------------------------------------
extern "C" void kernel_launch(void* const* d_in, const int* in_sizes, int n_in,
                              void* d_out, int out_size, void* d_ws, size_t ws_size,
                              hipStream_t stream)
{
    const float* x      = (const float*)d_in[0];
    const float* qkv_w  = (const float*)d_in[1];
    const float* qkv_b  = (const float*)d_in[2];
    const float* lepe_w = (const float*)d_in[3];
    const float* lepe_b = (const float*)d_in[4];
    const float* out_w  = (const float*)d_in[5];
    const float* out_b  = (const float*)d_in[6];
    float* out = (float*)d_out;

    char* ws = (char*)d_ws;
    float* qkvT = (float*)ws;                                   // 8*4096*1152 f32 = 151 MB
    float* cosv = (float*)(ws + 150994944);                     // 96*4096 f32
    int*   idx  = (int*)  (ws + 150994944 + 1572864);           // 96*4096 i32
    float* lepeT = out;  // borrow d_out (same 50MB size); final GEMM overwrites later

    // 1) QKV projection -> token-major qkvT[b][t][1152]
    dim3 g1(1152 / 128, 4096 / 128, 8);
    gemm_storeT_kernel<<<g1, 256, 0, stream>>>(qkv_w, x, qkv_b, qkvT,
                                               1152, 4096, 384,
                                               (long)384 * 4096, (long)4096 * 1152, 1152);
    // 2) LePE depthwise conv (token-major in/out) -> lepeT[b][t][384]
    lepe_kernel<<<dim3(24, 8, 8), 256, 0, stream>>>(qkvT, lepe_w, lepe_b, lepeT);
    // 3) cosine-to-class-mean per (b, head)
    cos_kernel<<<96, 256, 0, stream>>>(qkvT, cosv);
    // 4) stable ascending argsort
    sort_kernel<<<96, 512, 0, stream>>>(cosv, idx);
    // 5) clustered attention + lepe residual + inverse scatter (into q cols of qkvT)
    attn_kernel<<<dim3(16, 12, 8), 256, 0, stream>>>(qkvT, idx, lepeT);
    // 6) output projection, B = token-major res in qkvT q-region
    dim3 g2(384 / 128, 4096 / 128, 8);
    gemm_bt_kernel<<<g2, 256, 0, stream>>>(out_w, qkvT, out_b, out,
                                           384, 4096, 384,
                                           1152, (long)4096 * 1152, (long)384 * 4096);
}

// Round 3
// 683.273 us; speedup vs baseline: 1.6102x; 1.4416x over previous
//
#include <hip/hip_runtime.h>
#include <math.h>

#define SCALE_F 0.17677669529663687f   // 32^-0.5

using bf16x8 = __attribute__((ext_vector_type(8))) __bf16;
using f32x16 = __attribute__((ext_vector_type(16))) float;
using uint2e = __attribute__((ext_vector_type(2))) unsigned int;

__device__ inline unsigned int packbf(float a, float b) {
    __bf16 x = (__bf16)a, y = (__bf16)b;
    unsigned short ux = __builtin_bit_cast(unsigned short, x);
    unsigned short uy = __builtin_bit_cast(unsigned short, y);
    return (unsigned int)ux | ((unsigned int)uy << 16);
}
__device__ inline unsigned short f2bf(float x) {
    unsigned int u = __builtin_bit_cast(unsigned int, x);
    unsigned int r = (u + 0x7FFFu + ((u >> 16) & 1u)) >> 16;
    return (unsigned short)r;
}

// ---------------------------------------------------------------------------
// GEMM1: C[m][n] = sum_k A[m][k]*B[k][n] + bias[m], stored TRANSPOSED CT[n][m]
// ---------------------------------------------------------------------------
__global__ __launch_bounds__(256)
void gemm_storeT_kernel(const float* __restrict__ A, const float* __restrict__ Bmat,
                        const float* __restrict__ bias, float* __restrict__ CT,
                        int M, int N, int K, long strideB, long strideCT, int ldct)
{
    const int bm = blockIdx.x, bn = blockIdx.y, bz = blockIdx.z;
    const float* Bp = Bmat + (long)bz * strideB;
    float* Cp = CT + (long)bz * strideCT;
    __shared__ float As[16][132];
    __shared__ float Bs[16][132];
    const int tid = threadIdx.x;
    const int tx = tid & 15, ty = tid >> 4;
    const int m0 = bm * 128, n0 = bn * 128;
    float acc[8][8];
    #pragma unroll
    for (int i = 0; i < 8; ++i)
        #pragma unroll
        for (int j = 0; j < 8; ++j) acc[i][j] = 0.f;

    for (int k0 = 0; k0 < K; k0 += 16) {
        #pragma unroll
        for (int it = 0; it < 2; ++it) {
            int slot = tid + it * 256;
            int r = slot >> 2, cq = slot & 3;
            float4 av = *reinterpret_cast<const float4*>(&A[(long)(m0 + r) * K + k0 + cq * 4]);
            As[cq * 4 + 0][r] = av.x; As[cq * 4 + 1][r] = av.y;
            As[cq * 4 + 2][r] = av.z; As[cq * 4 + 3][r] = av.w;
        }
        #pragma unroll
        for (int it = 0; it < 2; ++it) {
            int slot = tid + it * 256;
            int r = slot >> 5, cq = slot & 31;
            *reinterpret_cast<float4*>(&Bs[r][cq * 4]) =
                *reinterpret_cast<const float4*>(&Bp[(long)(k0 + r) * N + n0 + cq * 4]);
        }
        __syncthreads();
        #pragma unroll
        for (int kk = 0; kk < 16; ++kk) {
            float a[8], b[8];
            *reinterpret_cast<float4*>(&a[0]) = *reinterpret_cast<const float4*>(&As[kk][ty * 8]);
            *reinterpret_cast<float4*>(&a[4]) = *reinterpret_cast<const float4*>(&As[kk][ty * 8 + 4]);
            *reinterpret_cast<float4*>(&b[0]) = *reinterpret_cast<const float4*>(&Bs[kk][tx * 8]);
            *reinterpret_cast<float4*>(&b[4]) = *reinterpret_cast<const float4*>(&Bs[kk][tx * 8 + 4]);
            #pragma unroll
            for (int i = 0; i < 8; ++i)
                #pragma unroll
                for (int j = 0; j < 8; ++j)
                    acc[i][j] += a[i] * b[j];
        }
        __syncthreads();
    }

    float bv[8];
    #pragma unroll
    for (int i = 0; i < 8; ++i) bv[i] = bias[m0 + ty * 8 + i];
    #pragma unroll
    for (int j = 0; j < 8; ++j) {
        long tok = n0 + tx * 8 + j;
        float* p = Cp + tok * ldct + m0 + ty * 8;
        float4 lo = make_float4(acc[0][j] + bv[0], acc[1][j] + bv[1], acc[2][j] + bv[2], acc[3][j] + bv[3]);
        float4 hi = make_float4(acc[4][j] + bv[4], acc[5][j] + bv[5], acc[6][j] + bv[6], acc[7][j] + bv[7]);
        *reinterpret_cast<float4*>(p) = lo;
        *reinterpret_cast<float4*>(p + 4) = hi;
    }
}

// ---------------------------------------------------------------------------
// GEMM2: C[m][n] = sum_k A[m][k]*BT[n][k] + bias[m]  (B token-major, strided)
// ---------------------------------------------------------------------------
__global__ __launch_bounds__(256)
void gemm_bt_kernel(const float* __restrict__ A, const float* __restrict__ BT,
                    const float* __restrict__ bias, float* __restrict__ C,
                    int M, int N, int K, int ldbt, long strideBT, long strideC)
{
    const int bm = blockIdx.x, bn = blockIdx.y, bz = blockIdx.z;
    const float* Bp = BT + (long)bz * strideBT;
    float* Cp = C + (long)bz * strideC;
    __shared__ float As[16][132];
    __shared__ float Bs[16][132];
    const int tid = threadIdx.x;
    const int tx = tid & 15, ty = tid >> 4;
    const int m0 = bm * 128, n0 = bn * 128;
    float acc[8][8];
    #pragma unroll
    for (int i = 0; i < 8; ++i)
        #pragma unroll
        for (int j = 0; j < 8; ++j) acc[i][j] = 0.f;

    for (int k0 = 0; k0 < K; k0 += 16) {
        #pragma unroll
        for (int it = 0; it < 2; ++it) {
            int slot = tid + it * 256;
            int r = slot >> 2, cq = slot & 3;
            float4 av = *reinterpret_cast<const float4*>(&A[(long)(m0 + r) * K + k0 + cq * 4]);
            As[cq * 4 + 0][r] = av.x; As[cq * 4 + 1][r] = av.y;
            As[cq * 4 + 2][r] = av.z; As[cq * 4 + 3][r] = av.w;
        }
        #pragma unroll
        for (int it = 0; it < 2; ++it) {
            int slot = tid + it * 256;
            int n = slot >> 2, q = slot & 3;
            float4 bv4 = *reinterpret_cast<const float4*>(&Bp[(long)(n0 + n) * ldbt + k0 + q * 4]);
            Bs[q * 4 + 0][n] = bv4.x; Bs[q * 4 + 1][n] = bv4.y;
            Bs[q * 4 + 2][n] = bv4.z; Bs[q * 4 + 3][n] = bv4.w;
        }
        __syncthreads();
        #pragma unroll
        for (int kk = 0; kk < 16; ++kk) {
            float a[8], b[8];
            *reinterpret_cast<float4*>(&a[0]) = *reinterpret_cast<const float4*>(&As[kk][ty * 8]);
            *reinterpret_cast<float4*>(&a[4]) = *reinterpret_cast<const float4*>(&As[kk][ty * 8 + 4]);
            *reinterpret_cast<float4*>(&b[0]) = *reinterpret_cast<const float4*>(&Bs[kk][tx * 8]);
            *reinterpret_cast<float4*>(&b[4]) = *reinterpret_cast<const float4*>(&Bs[kk][tx * 8 + 4]);
            #pragma unroll
            for (int i = 0; i < 8; ++i)
                #pragma unroll
                for (int j = 0; j < 8; ++j)
                    acc[i][j] += a[i] * b[j];
        }
        __syncthreads();
    }

    #pragma unroll
    for (int i = 0; i < 8; ++i) {
        float bv = bias[m0 + ty * 8 + i];
        float4 v0 = make_float4(acc[i][0] + bv, acc[i][1] + bv, acc[i][2] + bv, acc[i][3] + bv);
        float4 v1 = make_float4(acc[i][4] + bv, acc[i][5] + bv, acc[i][6] + bv, acc[i][7] + bv);
        float* crow = &Cp[(long)(m0 + ty * 8 + i) * N + n0 + tx * 8];
        *reinterpret_cast<float4*>(crow) = v0;
        *reinterpret_cast<float4*>(crow + 4) = v1;
    }
}

// ---------------------------------------------------------------------------
// Depthwise 5x5 conv (pad 2), token-major in/out.
// ---------------------------------------------------------------------------
__global__ __launch_bounds__(256)
void lepe_kernel(const float* __restrict__ qkvT, const float* __restrict__ w5,
                 const float* __restrict__ wb, float* __restrict__ lepeT)
{
    const int ch0 = blockIdx.x * 16;
    const int y0 = blockIdx.y * 8;
    const int b = blockIdx.z;
    const float* vb = qkvT + (long)b * 4096 * 1152 + 768 + ch0;
    float* dst = lepeT + (long)b * 4096 * 384 + ch0;
    __shared__ float tile[12 * 68 * 16];
    const int tid = threadIdx.x;

    for (int i = tid; i < 12 * 68 * 16; i += 256) {
        int pix = i >> 4, c = i & 15;
        int yy = pix / 68, xx = pix % 68;
        int gy = y0 + yy - 2, gx = xx - 2;
        float v = 0.f;
        if (gy >= 0 && gy < 64 && gx >= 0 && gx < 64)
            v = vb[(long)(gy * 64 + gx) * 1152 + c];
        tile[i] = v;
    }
    const int c = tid & 15, xo = tid >> 4;
    float f[25];
    #pragma unroll
    for (int j = 0; j < 25; ++j) f[j] = w5[(ch0 + c) * 25 + j];
    const float bv = wb[ch0 + c];
    __syncthreads();

    #pragma unroll
    for (int yy = 0; yy < 8; ++yy) {
        #pragma unroll
        for (int xq = 0; xq < 4; ++xq) {
            int x = xq * 16 + xo;
            float acc = bv;
            #pragma unroll
            for (int dy = 0; dy < 5; ++dy)
                #pragma unroll
                for (int dx = 0; dx < 5; ++dx)
                    acc += tile[((yy + dy) * 68 + (x + dx)) * 16 + c] * f[dy * 5 + dx];
            dst[(long)((y0 + yy) * 64 + x) * 384 + c] = acc;
        }
    }
}

// ---------------------------------------------------------------------------
// cos kernel (token-major reads). grid 96 x 256.
// ---------------------------------------------------------------------------
__global__ __launch_bounds__(256)
void cos_kernel(const float* __restrict__ qkvT, float* __restrict__ cosv)
{
    const int bn = blockIdx.x;
    const int b = bn / 12, n = bn % 12;
    const float* kb = qkvT + (long)b * 4096 * 1152 + 384 + n * 32;
    __shared__ float part[256][33];
    __shared__ float clsn[32];
    const int tid = threadIdx.x;
    float acc[32];
    #pragma unroll
    for (int d = 0; d < 32; ++d) acc[d] = 0.f;
    for (int i = 0; i < 16; ++i) {
        long tok = tid + i * 256;
        const float* kr = kb + tok * 1152;
        #pragma unroll
        for (int d = 0; d < 32; ++d) acc[d] += kr[d];
    }
    #pragma unroll
    for (int d = 0; d < 32; ++d) part[tid][d] = acc[d];
    __syncthreads();
    if (tid < 32) {
        double s = 0.0;
        for (int t = 0; t < 256; ++t) s += (double)part[t][tid];
        part[0][tid] = (float)s;
    }
    __syncthreads();
    if (tid == 0) {
        double nn = 0.0;
        for (int d = 0; d < 32; ++d) { double v = (double)part[0][d]; nn += v * v; }
        double inv = 1.0 / sqrt(nn > 1e-300 ? nn : 1e-300);
        for (int d = 0; d < 32; ++d) clsn[d] = (float)((double)part[0][d] * inv);
    }
    __syncthreads();
    for (int i = 0; i < 16; ++i) {
        long tok = tid + i * 256;
        const float* kr = kb + tok * 1152;
        double dot = 0.0, nrm = 0.0;
        #pragma unroll
        for (int d = 0; d < 32; ++d) {
            float kv = kr[d];
            dot += (double)clsn[d] * (double)kv;
            nrm += (double)kv * (double)kv;
        }
        double cv = dot / sqrt(nrm > 1e-300 ? nrm : 1e-300);
        cosv[(long)bn * 4096 + tok] = (float)cv;
    }
}

// ---------------------------------------------------------------------------
// Bitonic argsort ascending by (cos, idx) — matches stable jnp.argsort.
// ---------------------------------------------------------------------------
__global__ __launch_bounds__(512)
void sort_kernel(const float* __restrict__ cosv, int* __restrict__ idxo)
{
    const int bn = blockIdx.x;
    __shared__ float sv[4096];
    __shared__ int si[4096];
    const int tid = threadIdx.x;
    for (int i = tid; i < 4096; i += 512) { sv[i] = cosv[(long)bn * 4096 + i]; si[i] = i; }
    __syncthreads();
    for (int size = 2; size <= 4096; size <<= 1) {
        for (int stride = size >> 1; stride >= 1; stride >>= 1) {
            for (int i = tid; i < 2048; i += 512) {
                int lo = (i << 1) - (i & (stride - 1));
                int hi = lo + stride;
                bool asc = ((lo & size) == 0);
                float av = sv[lo], bvv = sv[hi];
                int ai = si[lo], bi = si[hi];
                bool agtb = (av > bvv) || (av == bvv && ai > bi);
                if (agtb == asc) {
                    sv[lo] = bvv; sv[hi] = av;
                    si[lo] = bi; si[hi] = ai;
                }
            }
            __syncthreads();
        }
    }
    for (int i = tid; i < 4096; i += 512) idxo[(long)bn * 4096 + i] = si[i];
}

// ---------------------------------------------------------------------------
// MFMA clustered attention. grid (16,12,8), 256 thr = 4 waves.
// S^T = K·Q^T via mfma_32x32x16_bf16 (lane owns a query row -> in-lane
// softmax, no max-sub needed: |s| <~ 2). P^T fed to PV mfma via
// cvt_pk + permlane32_swap (no LDS round-trip). V stored transposed in LDS.
// Epilogue: res = o/l + lepe scattered to original token (q cols of qkvT).
// ---------------------------------------------------------------------------
__global__ __launch_bounds__(256)
void attn_kernel(float* __restrict__ qkvT, const int* __restrict__ idxbuf,
                 const float* __restrict__ lepeT)
{
    const int cc = blockIdx.x, n = blockIdx.y, b = blockIdx.z;
    const int* ip = idxbuf + ((long)(b * 12 + n)) * 4096 + cc * 256;

    __shared__ unsigned short KsL[256][36];
    __shared__ unsigned short VsT[32][260];
    __shared__ int tokLds[256];

    const int tid = threadIdx.x;
    const int w = tid >> 6;
    const int lane = tid & 63;
    const int lo5 = lane & 31;
    const int hi = lane >> 5;
    const int hi8 = hi * 8;

    // ---- gather ----
    const int tk0 = ip[tid];
    tokLds[tid] = tk0;
    const float* base = qkvT + ((long)b * 4096 + tk0) * 1152 + n * 32;
    float4 qv[8];
    #pragma unroll
    for (int dq = 0; dq < 8; ++dq) {
        qv[dq] = *reinterpret_cast<const float4*>(base + dq * 4);
        float4 kv = *reinterpret_cast<const float4*>(base + 384 + dq * 4);
        float4 vv = *reinterpret_cast<const float4*>(base + 768 + dq * 4);
        ushort4 kp;
        kp.x = f2bf(kv.x * SCALE_F); kp.y = f2bf(kv.y * SCALE_F);
        kp.z = f2bf(kv.z * SCALE_F); kp.w = f2bf(kv.w * SCALE_F);
        *reinterpret_cast<ushort4*>(&KsL[tid][dq * 4]) = kp;
        VsT[dq * 4 + 0][tid] = f2bf(vv.x);
        VsT[dq * 4 + 1][tid] = f2bf(vv.y);
        VsT[dq * 4 + 2][tid] = f2bf(vv.z);
        VsT[dq * 4 + 3][tid] = f2bf(vv.w);
    }

    // ---- Q B-frags from own registers via permlane32_swap ----
    unsigned int Pq[16];
    #pragma unroll
    for (int j = 0; j < 8; ++j) {
        Pq[2 * j] = packbf(qv[j].x, qv[j].y);
        Pq[2 * j + 1] = packbf(qv[j].z, qv[j].w);
    }
    bf16x8 qf00, qf01, qf10, qf11;
    {
        unsigned int w0[2][4], w1[2][4];
        #pragma unroll
        for (int ks = 0; ks < 2; ++ks)
            #pragma unroll
            for (int j = 0; j < 4; ++j) {
                uint2e r = __builtin_amdgcn_permlane32_swap(Pq[ks * 8 + j], Pq[ks * 8 + 4 + j], false, false);
                w0[ks][j] = r[0];
                w1[ks][j] = r[1];
            }
        qf00 = __builtin_bit_cast(bf16x8, make_uint4(w0[0][0], w0[0][1], w0[0][2], w0[0][3]));
        qf01 = __builtin_bit_cast(bf16x8, make_uint4(w0[1][0], w0[1][1], w0[1][2], w0[1][3]));
        qf10 = __builtin_bit_cast(bf16x8, make_uint4(w1[0][0], w1[0][1], w1[0][2], w1[0][3]));
        qf11 = __builtin_bit_cast(bf16x8, make_uint4(w1[1][0], w1[1][1], w1[1][2], w1[1][3]));
    }
    __syncthreads();

    const f32x16 Z16 = {0,0,0,0,0,0,0,0,0,0,0,0,0,0,0,0};
    f32x16 o0 = Z16, o1 = Z16;
    float lsum0 = 0.f, lsum1 = 0.f;

#define LDFRAG(ARR, ROW, OFF) ({ \
    const unsigned short* _p = &ARR[ROW][OFF]; \
    union { bf16x8 v; ushort4 h[2]; } _u; \
    _u.h[0] = *reinterpret_cast<const ushort4*>(_p); \
    _u.h[1] = *reinterpret_cast<const ushort4*>(_p + 4); \
    _u.v; })

#define EXP16(S, LS) { _Pragma("unroll") for (int r = 0; r < 16; ++r) { float _e = __expf(S[r]); S[r] = _e; LS += _e; } }

#define MKPB(S, H) ({ \
    unsigned int _x0 = packbf(S[(H) * 8 + 0], S[(H) * 8 + 1]); \
    unsigned int _x1 = packbf(S[(H) * 8 + 2], S[(H) * 8 + 3]); \
    unsigned int _x2 = packbf(S[(H) * 8 + 4], S[(H) * 8 + 5]); \
    unsigned int _x3 = packbf(S[(H) * 8 + 6], S[(H) * 8 + 7]); \
    uint2e _r02 = __builtin_amdgcn_permlane32_swap(_x0, _x2, false, false); \
    uint2e _r13 = __builtin_amdgcn_permlane32_swap(_x1, _x3, false, false); \
    __builtin_bit_cast(bf16x8, make_uint4(_r02[0], _r13[0], _r02[1], _r13[1])); })

    for (int ch = 0; ch < 4; ++ch) {
        const int rb = ch * 64;
        f32x16 s00 = Z16, s01 = Z16, s10 = Z16, s11 = Z16;
        bf16x8 ka;
        ka = LDFRAG(KsL, rb + lo5, hi8);
        s00 = __builtin_amdgcn_mfma_f32_32x32x16_bf16(ka, qf00, s00, 0, 0, 0);
        s01 = __builtin_amdgcn_mfma_f32_32x32x16_bf16(ka, qf10, s01, 0, 0, 0);
        ka = LDFRAG(KsL, rb + lo5, 16 + hi8);
        s00 = __builtin_amdgcn_mfma_f32_32x32x16_bf16(ka, qf01, s00, 0, 0, 0);
        s01 = __builtin_amdgcn_mfma_f32_32x32x16_bf16(ka, qf11, s01, 0, 0, 0);
        ka = LDFRAG(KsL, rb + 32 + lo5, hi8);
        s10 = __builtin_amdgcn_mfma_f32_32x32x16_bf16(ka, qf00, s10, 0, 0, 0);
        s11 = __builtin_amdgcn_mfma_f32_32x32x16_bf16(ka, qf10, s11, 0, 0, 0);
        ka = LDFRAG(KsL, rb + 32 + lo5, 16 + hi8);
        s10 = __builtin_amdgcn_mfma_f32_32x32x16_bf16(ka, qf01, s10, 0, 0, 0);
        s11 = __builtin_amdgcn_mfma_f32_32x32x16_bf16(ka, qf11, s11, 0, 0, 0);

        EXP16(s00, lsum0); EXP16(s01, lsum1);
        EXP16(s10, lsum0); EXP16(s11, lsum1);

        bf16x8 va, pb0, pb1;
        va = LDFRAG(VsT, lo5, rb + 0 + hi8);
        pb0 = MKPB(s00, 0); pb1 = MKPB(s01, 0);
        o0 = __builtin_amdgcn_mfma_f32_32x32x16_bf16(va, pb0, o0, 0, 0, 0);
        o1 = __builtin_amdgcn_mfma_f32_32x32x16_bf16(va, pb1, o1, 0, 0, 0);
        va = LDFRAG(VsT, lo5, rb + 16 + hi8);
        pb0 = MKPB(s00, 1); pb1 = MKPB(s01, 1);
        o0 = __builtin_amdgcn_mfma_f32_32x32x16_bf16(va, pb0, o0, 0, 0, 0);
        o1 = __builtin_amdgcn_mfma_f32_32x32x16_bf16(va, pb1, o1, 0, 0, 0);
        va = LDFRAG(VsT, lo5, rb + 32 + hi8);
        pb0 = MKPB(s10, 0); pb1 = MKPB(s11, 0);
        o0 = __builtin_amdgcn_mfma_f32_32x32x16_bf16(va, pb0, o0, 0, 0, 0);
        o1 = __builtin_amdgcn_mfma_f32_32x32x16_bf16(va, pb1, o1, 0, 0, 0);
        va = LDFRAG(VsT, lo5, rb + 48 + hi8);
        pb0 = MKPB(s10, 1); pb1 = MKPB(s11, 1);
        o0 = __builtin_amdgcn_mfma_f32_32x32x16_bf16(va, pb0, o0, 0, 0, 0);
        o1 = __builtin_amdgcn_mfma_f32_32x32x16_bf16(va, pb1, o1, 0, 0, 0);
    }

    // ---- epilogue ----
    const float lf0 = lsum0 + __shfl_xor(lsum0, 32);
    const float lf1 = lsum1 + __shfl_xor(lsum1, 32);
    const float li0 = 1.f / lf0, li1 = 1.f / lf1;

    #pragma unroll
    for (int qt = 0; qt < 2; ++qt) {
        const int qrow = w * 64 + qt * 32 + lo5;
        const int tk = tokLds[qrow];
        float* ob = qkvT + ((long)b * 4096 + tk) * 1152 + n * 32;
        const float* lp = lepeT + ((long)b * 4096 + tk) * 384 + n * 32;
        const float li = qt ? li1 : li0;
        const f32x16& oo = qt ? o1 : o0;
        #pragma unroll
        for (int qd = 0; qd < 4; ++qd) {
            const int d0 = qd * 8 + hi * 4;
            float4 lv = *reinterpret_cast<const float4*>(lp + d0);
            float4 ov;
            ov.x = oo[qd * 4 + 0] * li + lv.x;
            ov.y = oo[qd * 4 + 1] * li + lv.y;
            ov.z = oo[qd * 4 + 2] * li + lv.z;
            ov.w = oo[qd * 4 + 3] * li + lv.w;
            *reinterpret_cast<float4*>(ob + d0) = ov;
        }
    }
#undef LDFRAG
#undef EXP16
#undef MKPB
}

// ---------------------------------------------------------------------------
extern "C" void kernel_launch(void* const* d_in, const int* in_sizes, int n_in,
                              void* d_out, int out_size, void* d_ws, size_t ws_size,
                              hipStream_t stream)
{
    const float* x      = (const float*)d_in[0];
    const float* qkv_w  = (const float*)d_in[1];
    const float* qkv_b  = (const float*)d_in[2];
    const float* lepe_w = (const float*)d_in[3];
    const float* lepe_b = (const float*)d_in[4];
    const float* out_w  = (const float*)d_in[5];
    const float* out_b  = (const float*)d_in[6];
    float* out = (float*)d_out;

    char* ws = (char*)d_ws;
    float* qkvT = (float*)ws;                                   // 8*4096*1152 f32 = 151 MB
    float* cosv = (float*)(ws + 150994944);                     // 96*4096 f32
    int*   idx  = (int*)  (ws + 150994944 + 1572864);           // 96*4096 i32
    float* lepeT = out;  // borrow d_out; final GEMM overwrites later

    dim3 g1(1152 / 128, 4096 / 128, 8);
    gemm_storeT_kernel<<<g1, 256, 0, stream>>>(qkv_w, x, qkv_b, qkvT,
                                               1152, 4096, 384,
                                               (long)384 * 4096, (long)4096 * 1152, 1152);
    lepe_kernel<<<dim3(24, 8, 8), 256, 0, stream>>>(qkvT, lepe_w, lepe_b, lepeT);
    cos_kernel<<<96, 256, 0, stream>>>(qkvT, cosv);
    sort_kernel<<<96, 512, 0, stream>>>(cosv, idx);
    attn_kernel<<<dim3(16, 12, 8), 256, 0, stream>>>(qkvT, idx, lepeT);
    dim3 g2(384 / 128, 4096 / 128, 8);
    gemm_bt_kernel<<<g2, 256, 0, stream>>>(out_w, qkvT, out_b, out,
                                           384, 4096, 384,
                                           1152, (long)4096 * 1152, (long)384 * 4096);
}

// Round 4
// 458.356 us; speedup vs baseline: 2.4003x; 1.4907x over previous
//
#include <hip/hip_runtime.h>
#include <math.h>

#define SCALE_F 0.17677669529663687f   // 32^-0.5

using bf16x8 = __attribute__((ext_vector_type(8))) __bf16;
using f32x4  = __attribute__((ext_vector_type(4))) float;
using f32x16 = __attribute__((ext_vector_type(16))) float;
using uint2e = __attribute__((ext_vector_type(2))) unsigned int;

__device__ inline unsigned short f2bf(float x) {
    unsigned int u = __builtin_bit_cast(unsigned int, x);
    unsigned int r = (u + 0x7FFFu + ((u >> 16) & 1u)) >> 16;
    return (unsigned short)r;
}
__device__ inline float bf2f(unsigned short u) {
    unsigned int x = ((unsigned int)u) << 16;
    return __builtin_bit_cast(float, x);
}
__device__ inline unsigned int packbf(float a, float b) {
    return (unsigned int)f2bf(a) | ((unsigned int)f2bf(b) << 16);
}
__device__ inline bf16x8 ldfrag(const unsigned short* p) {
    return __builtin_bit_cast(bf16x8, *reinterpret_cast<const uint4*>(p));
}

// ---------------------------------------------------------------------------
// fp32 GEMM (k-path only; bit-identical accumulation to rounds 1-3).
// C[m][n] = sum_k A[m_a_off+m][k]*B[k][n] + bias, stored CT[n][m-local].
// ---------------------------------------------------------------------------
__global__ __launch_bounds__(256)
void gemm_storeT_kernel(const float* __restrict__ A, const float* __restrict__ Bmat,
                        const float* __restrict__ bias, float* __restrict__ CT,
                        int M, int N, int K, long strideB, long strideCT, int ldct,
                        int m_a_off)
{
    const int bm = blockIdx.x, bn = blockIdx.y, bz = blockIdx.z;
    const float* Bp = Bmat + (long)bz * strideB;
    float* Cp = CT + (long)bz * strideCT;
    __shared__ float As[16][132];
    __shared__ float Bs[16][132];
    const int tid = threadIdx.x;
    const int tx = tid & 15, ty = tid >> 4;
    const int m0 = bm * 128, n0 = bn * 128;
    float acc[8][8];
    #pragma unroll
    for (int i = 0; i < 8; ++i)
        #pragma unroll
        for (int j = 0; j < 8; ++j) acc[i][j] = 0.f;

    for (int k0 = 0; k0 < K; k0 += 16) {
        #pragma unroll
        for (int it = 0; it < 2; ++it) {
            int slot = tid + it * 256;
            int r = slot >> 2, cq = slot & 3;
            float4 av = *reinterpret_cast<const float4*>(&A[(long)(m_a_off + m0 + r) * K + k0 + cq * 4]);
            As[cq * 4 + 0][r] = av.x; As[cq * 4 + 1][r] = av.y;
            As[cq * 4 + 2][r] = av.z; As[cq * 4 + 3][r] = av.w;
        }
        #pragma unroll
        for (int it = 0; it < 2; ++it) {
            int slot = tid + it * 256;
            int r = slot >> 5, cq = slot & 31;
            *reinterpret_cast<float4*>(&Bs[r][cq * 4]) =
                *reinterpret_cast<const float4*>(&Bp[(long)(k0 + r) * N + n0 + cq * 4]);
        }
        __syncthreads();
        #pragma unroll
        for (int kk = 0; kk < 16; ++kk) {
            float a[8], b[8];
            *reinterpret_cast<float4*>(&a[0]) = *reinterpret_cast<const float4*>(&As[kk][ty * 8]);
            *reinterpret_cast<float4*>(&a[4]) = *reinterpret_cast<const float4*>(&As[kk][ty * 8 + 4]);
            *reinterpret_cast<float4*>(&b[0]) = *reinterpret_cast<const float4*>(&Bs[kk][tx * 8]);
            *reinterpret_cast<float4*>(&b[4]) = *reinterpret_cast<const float4*>(&Bs[kk][tx * 8 + 4]);
            #pragma unroll
            for (int i = 0; i < 8; ++i)
                #pragma unroll
                for (int j = 0; j < 8; ++j)
                    acc[i][j] += a[i] * b[j];
        }
        __syncthreads();
    }

    float bv[8];
    #pragma unroll
    for (int i = 0; i < 8; ++i) bv[i] = bias[m_a_off + m0 + ty * 8 + i];
    #pragma unroll
    for (int j = 0; j < 8; ++j) {
        long tok = n0 + tx * 8 + j;
        float* p = Cp + tok * ldct + m0 + ty * 8;
        float4 lo = make_float4(acc[0][j] + bv[0], acc[1][j] + bv[1], acc[2][j] + bv[2], acc[3][j] + bv[3]);
        float4 hi = make_float4(acc[4][j] + bv[4], acc[5][j] + bv[5], acc[6][j] + bv[6], acc[7][j] + bv[7]);
        *reinterpret_cast<float4*>(p) = lo;
        *reinterpret_cast<float4*>(p + 4) = hi;
    }
}

// ---------------------------------------------------------------------------
// bf16 MFMA NT-GEMM: D[rowA][rowB] = sum_k A[rowA][k]*B[rowB][k], both k-contig.
// 128x128 tile, BK=32, 4 waves (2x2 of 64x64), 16x16x32 MFMA.
// SM=0: store bf16 at C[t=colB][m=rowA] (ldc 768), bias by rowA  (QV proj)
// SM=1: store f32  at C[m=colB][t=rowA] (ldc 4096), bias by colB (out proj)
// SPLIT: A,B given as hi/lo bf16 pairs; 3-term product (hi*hi+hi*lo+lo*hi).
// ---------------------------------------------------------------------------
template<bool SPLIT, int SM>
__global__ __launch_bounds__(256)
void mfma_nt_kernel(const unsigned short* __restrict__ Ah, const unsigned short* __restrict__ Al,
                    const unsigned short* __restrict__ Bh, const unsigned short* __restrict__ Bl,
                    const float* __restrict__ bias, void* __restrict__ Cout,
                    int K, int lda, int ldb,
                    long strideAb, long strideBb, long strideCb)
{
    extern __shared__ unsigned short smem[];
    unsigned short* As  = smem;            // [128][40]
    unsigned short* Bs  = smem + 5120;
    unsigned short* Asl = smem + 10240;
    unsigned short* Bsl = smem + 15360;
    const int bm = blockIdx.x, bn = blockIdx.y, bz = blockIdx.z;
    const unsigned short* Ap = Ah + (long)bz * strideAb;
    const unsigned short* Bp = Bh + (long)bz * strideBb;
    const unsigned short* Alp = nullptr;
    const unsigned short* Blp = nullptr;
    if constexpr (SPLIT) {
        Alp = Al + (long)bz * strideAb;
        Blp = Bl + (long)bz * strideBb;
    }
    const int tid = threadIdx.x;
    const int lane = tid & 63, wid = tid >> 6;
    const int wr = wid >> 1, wc = wid & 1;
    const int l15 = lane & 15, l4 = lane >> 4;
    const int m0 = bm * 128, n0 = bn * 128;

    const f32x4 Z4 = {0.f, 0.f, 0.f, 0.f};
    f32x4 acc[4][4];
    #pragma unroll
    for (int i = 0; i < 4; ++i)
        #pragma unroll
        for (int j = 0; j < 4; ++j) acc[i][j] = Z4;

    for (int k0 = 0; k0 < K; k0 += 32) {
        if (k0) __syncthreads();
        #pragma unroll
        for (int it = 0; it < 2; ++it) {
            int slot = tid + it * 256;
            int r = slot >> 2, cq = slot & 3;
            *reinterpret_cast<uint4*>(&As[r * 40 + cq * 8]) =
                *reinterpret_cast<const uint4*>(&Ap[(long)(m0 + r) * lda + k0 + cq * 8]);
            *reinterpret_cast<uint4*>(&Bs[r * 40 + cq * 8]) =
                *reinterpret_cast<const uint4*>(&Bp[(long)(n0 + r) * ldb + k0 + cq * 8]);
            if constexpr (SPLIT) {
                *reinterpret_cast<uint4*>(&Asl[r * 40 + cq * 8]) =
                    *reinterpret_cast<const uint4*>(&Alp[(long)(m0 + r) * lda + k0 + cq * 8]);
                *reinterpret_cast<uint4*>(&Bsl[r * 40 + cq * 8]) =
                    *reinterpret_cast<const uint4*>(&Blp[(long)(n0 + r) * ldb + k0 + cq * 8]);
            }
        }
        __syncthreads();

        bf16x8 af[4], bg[4], afl[4], bgl[4];
        #pragma unroll
        for (int f = 0; f < 4; ++f) {
            af[f] = ldfrag(&As[(wr * 64 + f * 16 + l15) * 40 + l4 * 8]);
            bg[f] = ldfrag(&Bs[(wc * 64 + f * 16 + l15) * 40 + l4 * 8]);
        }
        if constexpr (SPLIT) {
            #pragma unroll
            for (int f = 0; f < 4; ++f) {
                afl[f] = ldfrag(&Asl[(wr * 64 + f * 16 + l15) * 40 + l4 * 8]);
                bgl[f] = ldfrag(&Bsl[(wc * 64 + f * 16 + l15) * 40 + l4 * 8]);
            }
        }
        #pragma unroll
        for (int fi = 0; fi < 4; ++fi)
            #pragma unroll
            for (int fj = 0; fj < 4; ++fj) {
                acc[fi][fj] = __builtin_amdgcn_mfma_f32_16x16x32_bf16(af[fi], bg[fj], acc[fi][fj], 0, 0, 0);
                if constexpr (SPLIT) {
                    acc[fi][fj] = __builtin_amdgcn_mfma_f32_16x16x32_bf16(af[fi], bgl[fj], acc[fi][fj], 0, 0, 0);
                    acc[fi][fj] = __builtin_amdgcn_mfma_f32_16x16x32_bf16(afl[fi], bg[fj], acc[fi][fj], 0, 0, 0);
                }
            }
    }

    if constexpr (SM == 0) {
        unsigned short* Cq = (unsigned short*)Cout + (long)bz * strideCb;
        #pragma unroll
        for (int fi = 0; fi < 4; ++fi)
            #pragma unroll
            for (int fj = 0; fj < 4; ++fj) {
                const int m = m0 + wr * 64 + fi * 16 + l4 * 4;
                const int t = n0 + wc * 64 + fj * 16 + l15;
                ushort4 h;
                h.x = f2bf(acc[fi][fj][0] + bias[m + 0]);
                h.y = f2bf(acc[fi][fj][1] + bias[m + 1]);
                h.z = f2bf(acc[fi][fj][2] + bias[m + 2]);
                h.w = f2bf(acc[fi][fj][3] + bias[m + 3]);
                *reinterpret_cast<ushort4*>(&Cq[(long)t * 768 + m]) = h;
            }
    } else {
        float* Cf = (float*)Cout + (long)bz * strideCb;
        #pragma unroll
        for (int fi = 0; fi < 4; ++fi)
            #pragma unroll
            for (int fj = 0; fj < 4; ++fj) {
                const int t = m0 + wr * 64 + fi * 16 + l4 * 4;
                const int m = n0 + wc * 64 + fj * 16 + l15;
                const float bv = bias[m];
                float4 v = make_float4(acc[fi][fj][0] + bv, acc[fi][fj][1] + bv,
                                       acc[fi][fj][2] + bv, acc[fi][fj][3] + bv);
                *reinterpret_cast<float4*>(&Cf[(long)m * 4096 + t]) = v;
            }
    }
}

// ---------------------------------------------------------------------------
// Weight conversion: Wqv bf16 (q,v rows of qkv_w), qv bias gather,
// out_w split hi/lo bf16.
// ---------------------------------------------------------------------------
__global__ __launch_bounds__(256)
void convert_w_kernel(const float* __restrict__ qkv_w, const float* __restrict__ qkv_b,
                      const float* __restrict__ out_w,
                      unsigned short* __restrict__ Wqv, float* __restrict__ qvb,
                      unsigned short* __restrict__ owh, unsigned short* __restrict__ owl)
{
    const int total = 294912 + 147456 + 768;
    for (int i = blockIdx.x * 256 + threadIdx.x; i < total; i += gridDim.x * 256) {
        if (i < 294912) {
            int m = i / 384, k = i - m * 384;
            int src = (m < 384) ? m : m + 384;
            Wqv[i] = f2bf(qkv_w[(long)src * 384 + k]);
        } else if (i < 294912 + 147456) {
            int o = i - 294912;
            float w = out_w[o];
            unsigned short h = f2bf(w);
            owh[o] = h;
            owl[o] = f2bf(w - bf2f(h));
        } else {
            int m = i - 294912 - 147456;
            qvb[m] = qkv_b[(m < 384) ? m : m + 384];
        }
    }
}

// ---------------------------------------------------------------------------
// x [b][384][4096] fp32 -> xbT [b][4096][384] bf16 (LDS 64x64 transpose)
// ---------------------------------------------------------------------------
__global__ __launch_bounds__(256)
void transpose_x_kernel(const float* __restrict__ x, unsigned short* __restrict__ xbT)
{
    const int t0 = blockIdx.x * 64, c0 = blockIdx.y * 64, b = blockIdx.z;
    __shared__ float tl[64][65];
    const int tid = threadIdx.x;
    #pragma unroll
    for (int i = 0; i < 16; ++i) {
        int cr = (tid >> 6) + i * 4, tc = tid & 63;
        tl[cr][tc] = x[((long)b * 384 + c0 + cr) * 4096 + t0 + tc];
    }
    __syncthreads();
    #pragma unroll
    for (int i = 0; i < 8; ++i) {
        int tr = (tid >> 5) + i * 8, c2 = (tid & 31) * 2;
        unsigned int u = (unsigned int)f2bf(tl[c2][tr]) | ((unsigned int)f2bf(tl[c2 + 1][tr]) << 16);
        *reinterpret_cast<unsigned int*>(&xbT[((long)b * 4096 + t0 + tr) * 384 + c0 + c2]) = u;
    }
}

// ---------------------------------------------------------------------------
// Depthwise 5x5 conv (pad 2), v from qvB (bf16), out lepeT (bf16).
// ---------------------------------------------------------------------------
__global__ __launch_bounds__(256)
void lepe_kernel(const unsigned short* __restrict__ qvB, const float* __restrict__ w5,
                 const float* __restrict__ wb, unsigned short* __restrict__ lepeT)
{
    const int ch0 = blockIdx.x * 16;
    const int y0 = blockIdx.y * 8;
    const int b = blockIdx.z;
    const unsigned short* vb = qvB + (long)b * 4096 * 768 + 384 + ch0;
    unsigned short* dst = lepeT + (long)b * 4096 * 384 + ch0;
    __shared__ float tile[12 * 68 * 16];
    const int tid = threadIdx.x;

    for (int i = tid; i < 12 * 68 * 16; i += 256) {
        int pix = i >> 4, c = i & 15;
        int yy = pix / 68, xx = pix % 68;
        int gy = y0 + yy - 2, gx = xx - 2;
        float v = 0.f;
        if (gy >= 0 && gy < 64 && gx >= 0 && gx < 64)
            v = bf2f(vb[(long)(gy * 64 + gx) * 768 + c]);
        tile[i] = v;
    }
    const int c = tid & 15, xo = tid >> 4;
    float f[25];
    #pragma unroll
    for (int j = 0; j < 25; ++j) f[j] = w5[(ch0 + c) * 25 + j];
    const float bv = wb[ch0 + c];
    __syncthreads();

    #pragma unroll
    for (int yy = 0; yy < 8; ++yy) {
        #pragma unroll
        for (int xq = 0; xq < 4; ++xq) {
            int x = xq * 16 + xo;
            float acc = bv;
            #pragma unroll
            for (int dy = 0; dy < 5; ++dy)
                #pragma unroll
                for (int dx = 0; dx < 5; ++dx)
                    acc += tile[((yy + dy) * 68 + (x + dx)) * 16 + c] * f[dy * 5 + dx];
            dst[(long)((y0 + yy) * 64 + x) * 384 + c] = f2bf(acc);
        }
    }
}

// ---------------------------------------------------------------------------
// cos kernel: reads Kf32 [b][t][384] (bit-identical k values).
// ---------------------------------------------------------------------------
__global__ __launch_bounds__(256)
void cos_kernel(const float* __restrict__ Kf32, float* __restrict__ cosv)
{
    const int bn = blockIdx.x;
    const int b = bn / 12, n = bn % 12;
    const float* kb = Kf32 + (long)b * 4096 * 384 + n * 32;
    __shared__ float part[256][33];
    __shared__ float clsn[32];
    const int tid = threadIdx.x;
    float acc[32];
    #pragma unroll
    for (int d = 0; d < 32; ++d) acc[d] = 0.f;
    for (int i = 0; i < 16; ++i) {
        long tok = tid + i * 256;
        const float* kr = kb + tok * 384;
        #pragma unroll
        for (int d = 0; d < 32; ++d) acc[d] += kr[d];
    }
    #pragma unroll
    for (int d = 0; d < 32; ++d) part[tid][d] = acc[d];
    __syncthreads();
    if (tid < 32) {
        double s = 0.0;
        for (int t = 0; t < 256; ++t) s += (double)part[t][tid];
        part[0][tid] = (float)s;
    }
    __syncthreads();
    if (tid == 0) {
        double nn = 0.0;
        for (int d = 0; d < 32; ++d) { double v = (double)part[0][d]; nn += v * v; }
        double inv = 1.0 / sqrt(nn > 1e-300 ? nn : 1e-300);
        for (int d = 0; d < 32; ++d) clsn[d] = (float)((double)part[0][d] * inv);
    }
    __syncthreads();
    for (int i = 0; i < 16; ++i) {
        long tok = tid + i * 256;
        const float* kr = kb + tok * 384;
        double dot = 0.0, nrm = 0.0;
        #pragma unroll
        for (int d = 0; d < 32; ++d) {
            float kv = kr[d];
            dot += (double)clsn[d] * (double)kv;
            nrm += (double)kv * (double)kv;
        }
        double cv = dot / sqrt(nrm > 1e-300 ? nrm : 1e-300);
        cosv[(long)bn * 4096 + tok] = (float)cv;
    }
}

// ---------------------------------------------------------------------------
// Bitonic argsort ascending by (cos, idx) — matches stable jnp.argsort.
// ---------------------------------------------------------------------------
__global__ __launch_bounds__(512)
void sort_kernel(const float* __restrict__ cosv, int* __restrict__ idxo)
{
    const int bn = blockIdx.x;
    __shared__ float sv[4096];
    __shared__ int si[4096];
    const int tid = threadIdx.x;
    for (int i = tid; i < 4096; i += 512) { sv[i] = cosv[(long)bn * 4096 + i]; si[i] = i; }
    __syncthreads();
    for (int size = 2; size <= 4096; size <<= 1) {
        for (int stride = size >> 1; stride >= 1; stride >>= 1) {
            for (int i = tid; i < 2048; i += 512) {
                int lo = (i << 1) - (i & (stride - 1));
                int hi = lo + stride;
                bool asc = ((lo & size) == 0);
                float av = sv[lo], bvv = sv[hi];
                int ai = si[lo], bi = si[hi];
                bool agtb = (av > bvv) || (av == bvv && ai > bi);
                if (agtb == asc) {
                    sv[lo] = bvv; sv[hi] = av;
                    si[lo] = bi; si[hi] = ai;
                }
            }
            __syncthreads();
        }
    }
    for (int i = tid; i < 4096; i += 512) idxo[(long)bn * 4096 + i] = si[i];
}

// ---------------------------------------------------------------------------
// MFMA clustered attention. grid (16,12,8), 256 thr = 4 waves.
// q,v bf16 from qvB; k fp32 from Kf32 (scaled->bf16). res = o/l + lepe
// written as bf16 hi/lo pair over the dead q/v channels of qvB (per-head
// channel slices are disjoint -> race-free).
// ---------------------------------------------------------------------------
__global__ __launch_bounds__(256)
void attn_kernel(const float* __restrict__ Kf32, unsigned short* __restrict__ qvB,
                 const int* __restrict__ idxbuf, const unsigned short* __restrict__ lepeT)
{
    const int cc = blockIdx.x, n = blockIdx.y, b = blockIdx.z;
    const int* ip = idxbuf + ((long)(b * 12 + n)) * 4096 + cc * 256;

    __shared__ unsigned short KsL[256][36];
    __shared__ unsigned short VsT[32][260];
    __shared__ int tokLds[256];

    const int tid = threadIdx.x;
    const int w = tid >> 6;
    const int lane = tid & 63;
    const int lo5 = lane & 31;
    const int hi = lane >> 5;
    const int hi8 = hi * 8;

    // ---- gather ----
    const int tk0 = ip[tid];
    tokLds[tid] = tk0;
    const long tb = (long)b * 4096 + tk0;
    const unsigned short* qrow = qvB + tb * 768 + n * 32;
    const float* krow = Kf32 + tb * 384 + n * 32;

    unsigned int Pq[16];
    #pragma unroll
    for (int i = 0; i < 4; ++i) {
        uint4 qu = *reinterpret_cast<const uint4*>(qrow + i * 8);
        Pq[4 * i + 0] = qu.x; Pq[4 * i + 1] = qu.y;
        Pq[4 * i + 2] = qu.z; Pq[4 * i + 3] = qu.w;
    }
    #pragma unroll
    for (int dq = 0; dq < 8; ++dq) {
        float4 kv = *reinterpret_cast<const float4*>(krow + dq * 4);
        ushort4 kp;
        kp.x = f2bf(kv.x * SCALE_F); kp.y = f2bf(kv.y * SCALE_F);
        kp.z = f2bf(kv.z * SCALE_F); kp.w = f2bf(kv.w * SCALE_F);
        *reinterpret_cast<ushort4*>(&KsL[tid][dq * 4]) = kp;
    }
    {
        union { uint4 u[4]; unsigned short s[32]; } vv;
        const unsigned short* vrow = qrow + 384;
        #pragma unroll
        for (int i = 0; i < 4; ++i) vv.u[i] = *reinterpret_cast<const uint4*>(vrow + i * 8);
        #pragma unroll
        for (int j = 0; j < 32; ++j) VsT[j][tid] = vv.s[j];
    }

    // ---- Q B-frags from own registers via permlane32_swap ----
    bf16x8 qf00, qf01, qf10, qf11;
    {
        unsigned int w0[2][4], w1[2][4];
        #pragma unroll
        for (int ks = 0; ks < 2; ++ks)
            #pragma unroll
            for (int j = 0; j < 4; ++j) {
                uint2e r = __builtin_amdgcn_permlane32_swap(Pq[ks * 8 + j], Pq[ks * 8 + 4 + j], false, false);
                w0[ks][j] = r[0];
                w1[ks][j] = r[1];
            }
        qf00 = __builtin_bit_cast(bf16x8, make_uint4(w0[0][0], w0[0][1], w0[0][2], w0[0][3]));
        qf01 = __builtin_bit_cast(bf16x8, make_uint4(w0[1][0], w0[1][1], w0[1][2], w0[1][3]));
        qf10 = __builtin_bit_cast(bf16x8, make_uint4(w1[0][0], w1[0][1], w1[0][2], w1[0][3]));
        qf11 = __builtin_bit_cast(bf16x8, make_uint4(w1[1][0], w1[1][1], w1[1][2], w1[1][3]));
    }
    __syncthreads();

    const f32x16 Z16 = {0,0,0,0,0,0,0,0,0,0,0,0,0,0,0,0};
    f32x16 o0 = Z16, o1 = Z16;
    float lsum0 = 0.f, lsum1 = 0.f;

#define LDFRAG(ARR, ROW, OFF) ({ \
    const unsigned short* _p = &ARR[ROW][OFF]; \
    union { bf16x8 v; ushort4 h[2]; } _u; \
    _u.h[0] = *reinterpret_cast<const ushort4*>(_p); \
    _u.h[1] = *reinterpret_cast<const ushort4*>(_p + 4); \
    _u.v; })

#define EXP16(S, LS) { _Pragma("unroll") for (int r = 0; r < 16; ++r) { float _e = __expf(S[r]); S[r] = _e; LS += _e; } }

#define MKPB(S, H) ({ \
    unsigned int _x0 = packbf(S[(H) * 8 + 0], S[(H) * 8 + 1]); \
    unsigned int _x1 = packbf(S[(H) * 8 + 2], S[(H) * 8 + 3]); \
    unsigned int _x2 = packbf(S[(H) * 8 + 4], S[(H) * 8 + 5]); \
    unsigned int _x3 = packbf(S[(H) * 8 + 6], S[(H) * 8 + 7]); \
    uint2e _r02 = __builtin_amdgcn_permlane32_swap(_x0, _x2, false, false); \
    uint2e _r13 = __builtin_amdgcn_permlane32_swap(_x1, _x3, false, false); \
    __builtin_bit_cast(bf16x8, make_uint4(_r02[0], _r13[0], _r02[1], _r13[1])); })

    for (int ch = 0; ch < 4; ++ch) {
        const int rb = ch * 64;
        f32x16 s00 = Z16, s01 = Z16, s10 = Z16, s11 = Z16;
        bf16x8 ka;
        ka = LDFRAG(KsL, rb + lo5, hi8);
        s00 = __builtin_amdgcn_mfma_f32_32x32x16_bf16(ka, qf00, s00, 0, 0, 0);
        s01 = __builtin_amdgcn_mfma_f32_32x32x16_bf16(ka, qf10, s01, 0, 0, 0);
        ka = LDFRAG(KsL, rb + lo5, 16 + hi8);
        s00 = __builtin_amdgcn_mfma_f32_32x32x16_bf16(ka, qf01, s00, 0, 0, 0);
        s01 = __builtin_amdgcn_mfma_f32_32x32x16_bf16(ka, qf11, s01, 0, 0, 0);
        ka = LDFRAG(KsL, rb + 32 + lo5, hi8);
        s10 = __builtin_amdgcn_mfma_f32_32x32x16_bf16(ka, qf00, s10, 0, 0, 0);
        s11 = __builtin_amdgcn_mfma_f32_32x32x16_bf16(ka, qf10, s11, 0, 0, 0);
        ka = LDFRAG(KsL, rb + 32 + lo5, 16 + hi8);
        s10 = __builtin_amdgcn_mfma_f32_32x32x16_bf16(ka, qf01, s10, 0, 0, 0);
        s11 = __builtin_amdgcn_mfma_f32_32x32x16_bf16(ka, qf11, s11, 0, 0, 0);

        EXP16(s00, lsum0); EXP16(s01, lsum1);
        EXP16(s10, lsum0); EXP16(s11, lsum1);

        bf16x8 va, pb0, pb1;
        va = LDFRAG(VsT, lo5, rb + 0 + hi8);
        pb0 = MKPB(s00, 0); pb1 = MKPB(s01, 0);
        o0 = __builtin_amdgcn_mfma_f32_32x32x16_bf16(va, pb0, o0, 0, 0, 0);
        o1 = __builtin_amdgcn_mfma_f32_32x32x16_bf16(va, pb1, o1, 0, 0, 0);
        va = LDFRAG(VsT, lo5, rb + 16 + hi8);
        pb0 = MKPB(s00, 1); pb1 = MKPB(s01, 1);
        o0 = __builtin_amdgcn_mfma_f32_32x32x16_bf16(va, pb0, o0, 0, 0, 0);
        o1 = __builtin_amdgcn_mfma_f32_32x32x16_bf16(va, pb1, o1, 0, 0, 0);
        va = LDFRAG(VsT, lo5, rb + 32 + hi8);
        pb0 = MKPB(s10, 0); pb1 = MKPB(s11, 0);
        o0 = __builtin_amdgcn_mfma_f32_32x32x16_bf16(va, pb0, o0, 0, 0, 0);
        o1 = __builtin_amdgcn_mfma_f32_32x32x16_bf16(va, pb1, o1, 0, 0, 0);
        va = LDFRAG(VsT, lo5, rb + 48 + hi8);
        pb0 = MKPB(s10, 1); pb1 = MKPB(s11, 1);
        o0 = __builtin_amdgcn_mfma_f32_32x32x16_bf16(va, pb0, o0, 0, 0, 0);
        o1 = __builtin_amdgcn_mfma_f32_32x32x16_bf16(va, pb1, o1, 0, 0, 0);
    }

    // ---- epilogue: res = o/l + lepe -> bf16 hi/lo into qvB ----
    const float lf0 = lsum0 + __shfl_xor(lsum0, 32);
    const float lf1 = lsum1 + __shfl_xor(lsum1, 32);
    const float li0 = 1.f / lf0, li1 = 1.f / lf1;

    #pragma unroll
    for (int qt = 0; qt < 2; ++qt) {
        const int qrix = w * 64 + qt * 32 + lo5;
        const int tk = tokLds[qrix];
        const long tb2 = (long)b * 4096 + tk;
        unsigned short* resrow = qvB + tb2 * 768;
        const unsigned short* lp = lepeT + tb2 * 384 + n * 32;
        const float li = qt ? li1 : li0;
        const f32x16& oo = qt ? o1 : o0;
        #pragma unroll
        for (int qd = 0; qd < 4; ++qd) {
            const int d0 = qd * 8 + hi * 4;
            ushort4 lv = *reinterpret_cast<const ushort4*>(lp + d0);
            float r0 = oo[qd * 4 + 0] * li + bf2f(lv.x);
            float r1 = oo[qd * 4 + 1] * li + bf2f(lv.y);
            float r2 = oo[qd * 4 + 2] * li + bf2f(lv.z);
            float r3 = oo[qd * 4 + 3] * li + bf2f(lv.w);
            unsigned short h0 = f2bf(r0), h1 = f2bf(r1), h2 = f2bf(r2), h3 = f2bf(r3);
            ushort4 hh = {h0, h1, h2, h3};
            ushort4 ll = {f2bf(r0 - bf2f(h0)), f2bf(r1 - bf2f(h1)),
                          f2bf(r2 - bf2f(h2)), f2bf(r3 - bf2f(h3))};
            *reinterpret_cast<ushort4*>(resrow + n * 32 + d0) = hh;
            *reinterpret_cast<ushort4*>(resrow + 384 + n * 32 + d0) = ll;
        }
    }
#undef LDFRAG
#undef EXP16
#undef MKPB
}

// ---------------------------------------------------------------------------
extern "C" void kernel_launch(void* const* d_in, const int* in_sizes, int n_in,
                              void* d_out, int out_size, void* d_ws, size_t ws_size,
                              hipStream_t stream)
{
    const float* x      = (const float*)d_in[0];
    const float* qkv_w  = (const float*)d_in[1];
    const float* qkv_b  = (const float*)d_in[2];
    const float* lepe_w = (const float*)d_in[3];
    const float* lepe_b = (const float*)d_in[4];
    const float* out_w  = (const float*)d_in[5];
    const float* out_b  = (const float*)d_in[6];
    float* out = (float*)d_out;

    char* ws = (char*)d_ws;
    float*          Kf32 = (float*)ws;                                  // 50331648 B
    unsigned short* qvB  = (unsigned short*)(ws + 50331648);            // 50331648 B
    float*          cosv = (float*)(ws + 100663296);                    // 1572864 B
    int*            idx  = (int*)(ws + 102236160);                      // 1572864 B
    unsigned short* Wqv  = (unsigned short*)(ws + 103809024);           // 589824 B
    unsigned short* owh  = (unsigned short*)(ws + 104398848);           // 294912 B
    unsigned short* owl  = (unsigned short*)(ws + 104693760);           // 294912 B
    float*          qvb  = (float*)(ws + 104988672);                    // 3072 B

    unsigned short* xbT   = (unsigned short*)d_out;                     // 25165824 B (dead before out-proj)
    unsigned short* lepeT = (unsigned short*)d_out + 12582912;          // 25165824 B (dead before out-proj)

    // 1) weight conversions
    convert_w_kernel<<<1731, 256, 0, stream>>>(qkv_w, qkv_b, out_w, Wqv, qvb, owh, owl);
    // 2) x -> token-major bf16
    transpose_x_kernel<<<dim3(64, 6, 8), 256, 0, stream>>>(x, xbT);
    // 3) k projection, exact fp32 (bit-identical to rounds 1-3)
    gemm_storeT_kernel<<<dim3(3, 32, 8), 256, 0, stream>>>(qkv_w, x, qkv_b, Kf32,
                                                           1152, 4096, 384,
                                                           (long)384 * 4096, (long)4096 * 384, 384, 384);
    // 4) q,v projection, bf16 MFMA -> qvB [b][t][768] bf16
    mfma_nt_kernel<false, 0><<<dim3(6, 32, 8), 256, 20480, stream>>>(
        Wqv, nullptr, xbT, nullptr, qvb, qvB,
        384, 384, 384, 0L, (long)4096 * 384, (long)4096 * 768);
    // 5) LePE depthwise conv (v bf16 -> lepeT bf16)
    lepe_kernel<<<dim3(24, 8, 8), 256, 0, stream>>>(qvB, lepe_w, lepe_b, lepeT);
    // 6) cosine-to-class-mean per (b, head)
    cos_kernel<<<96, 256, 0, stream>>>(Kf32, cosv);
    // 7) stable ascending argsort
    sort_kernel<<<96, 512, 0, stream>>>(cosv, idx);
    // 8) clustered attention + lepe residual; res -> bf16 hi/lo over qvB
    attn_kernel<<<dim3(16, 12, 8), 256, 0, stream>>>(Kf32, qvB, idx, lepeT);
    // 9) output projection, split-bf16 (3-term) MFMA -> out (overwrites xbT/lepeT region)
    mfma_nt_kernel<true, 1><<<dim3(32, 3, 8), 256, 40960, stream>>>(
        qvB, qvB + 384, owh, owl, out_b, out,
        384, 768, 384, (long)4096 * 768, 0L, (long)384 * 4096);
}